// Round 12
// baseline (231.586 us; speedup 1.0000x reference)
//
#include <hip/hip_runtime.h>

#define HH 192
#define WW 256
#define TH 8              // rows per block = waves per block
#define CCH 4             // channels per chunk
#define NCHUNK 16         // 64 / 4
#define THREADS 512       // 8 waves; wave = tile row
#define CHSTEP (CCH * HH * WW)
// x2 halo row: cols -4..259 = 264 floats = 66 16B-units per row
#define ROWF 264
#define CHF  (TH * ROWF)        // 2112 floats per channel
#define BUFF (CCH * CHF)        // 8448 floats per buffer
#define UNITS_PER_CHUNK (CCH * TH * 66)   // 2112 units = 33 strips of 64

typedef float f4 __attribute__((ext_vector_type(4)));

// async global->LDS, 16B per lane, dest = wave-uniform base + lane*16
#define GLL(gp, lp) __builtin_amdgcn_global_load_lds(                        \
    (const __attribute__((address_space(1))) unsigned int*)(gp),            \
    (__attribute__((address_space(3))) unsigned int*)(lp), 16, 0, 0)

// R12 restructure: i-shift moved from wave-dim to grid-dim (9x blocks, i
// fastest -> sibling blocks share tile data in L2/L3).
//  - full-width tile (8 rows x 256): no w-halo waste; ds_reads are
//    wave-uniform in row -> 64 consecutive lanes -> conflict-free by
//    construction (R8-R10: stride games never got conflicts to 0).
//  - fixed i per block: x2 needs exactly 8 rows (no row halo), and each x1
//    value is used by exactly ONE thread -> x1 goes global->reg directly,
//    LDS carries only x2 (3 b128/cc/lane vs 4; R7's direct-x1 failure was
//    the 9x wave redundancy, absent here).
//  - 512-thread blocks dodge the 576-thread 84-VGPR wall (R2-R5);
//    67.6KB LDS -> 2 blocks/CU co-residency.
__global__ __attribute__((amdgpu_flat_work_group_size(512, 512),
                          amdgpu_waves_per_eu(2, 4)))
void cost_volume_kernel(
    const float* __restrict__ x1, const float* __restrict__ x2,
    float* __restrict__ out)
{
    __shared__ __align__(16) float smem[2 * BUFF];   // 67584 B

    const int tid  = threadIdx.x;
    const int wave = tid >> 6;      // 0..7 = tile row
    const int lane = tid & 63;      // 64 col-groups of 4 px

    const int bid = blockIdx.x;
    const int ib  = bid % 9;        // i + 4, fastest dim for L2/L3 reuse
    const int ht  = (bid / 9) % 24;
    const int b   = bid / 216;
    const int h0  = ht * TH;

    // ---- x2 staging descriptors: 33 strips of 64 units, chunk-invariant ----
    // unit u -> ch = u/528, row = (u%528)/66, cu = u%66; col = cu*4 - 4.
    // LDS float offset = u*4 (linear). valid: cu in [1,64] (cu=0/65 are
    // pure halo -> stay pre-zeroed), row in-bounds for this i.
    auto desc2 = [&](int s, int& goff) {   // goff = -1 if masked
        const int u = (s << 6) + lane;
        const int ch = u / 528, rem = u % 528;
        const int row = rem / 66, cu = rem % 66;
        const int hg = h0 + row + 4 - ib;
        const bool v = (cu >= 1) & (cu <= 64) & (hg >= 0) & (hg < HH);
        goff = v ? (((b * 64 + ch) * HH + hg) * WW + (cu * 4 - 4)) : -1;
    };
    // wave w handles strips w, w+8, w+16, w+24; wave 0 also strip 32.
    int gA, gB, gC, gD, gE;
    desc2(wave,      gA);
    desc2(wave + 8,  gB);
    desc2(wave + 16, gC);
    desc2(wave + 24, gD);
    desc2(32,        gE);
    const bool hE = (wave == 0);

    auto issue = [&](int nb, int n) {
        const int cofs = n * CHSTEP;
        float* const base = smem + nb * BUFF;
        if (gA >= 0) GLL(x2 + gA + cofs, base + (wave << 8));
        if (gB >= 0) GLL(x2 + gB + cofs, base + ((wave + 8) << 8));
        if (gC >= 0) GLL(x2 + gC + cofs, base + ((wave + 16) << 8));
        if (gD >= 0) GLL(x2 + gD + cofs, base + ((wave + 24) << 8));
        if (hE & (gE >= 0)) GLL(x2 + gE + cofs, base + (32 << 8));
    };

    // ---- pre-zero LDS (halo/OOB slots persist as zeros) ----
    const f4 z4 = {0.f, 0.f, 0.f, 0.f};
    for (int z = tid; z < 2 * BUFF / 4; z += THREADS) ((f4*)smem)[z] = z4;
    __syncthreads();

    issue(0, 0);
    __syncthreads();   // drains vmcnt(0) before s_barrier

    f4 acc0 = z4, acc1 = z4, acc2 = z4, acc3 = z4, acc4 = z4,
       acc5 = z4, acc6 = z4, acc7 = z4, acc8 = z4;

    // x1 direct-load base: this thread's 4 px, channel 0
    const float* x1p = x1 + ((long)(b * 64) * HH + (h0 + wave)) * WW + lane * 4;

    for (int n = 0; n < NCHUNK; ++n) {
        if (n + 1 < NCHUNK) issue((n + 1) & 1, n + 1);
        // wave reads ITS row: staged row r holds x2 global row (h0+r)-i
        const float* sb2 = smem + (n & 1) * BUFF + wave * ROWF + lane * 4;
        const float* x1c = x1p + (long)n * CHSTEP;
#pragma unroll
        for (int cc = 0; cc < CCH; ++cc) {
            const f4 av  = *(const f4*)(x1c + cc * (HH * WW));  // global, L1/L2
            const f4 xv0 = *(const f4*)(sb2 + cc * CHF);
            const f4 xv1 = *(const f4*)(sb2 + cc * CHF + 4);
            const f4 xv2 = *(const f4*)(sb2 + cc * CHF + 8);
            // px p (w = lane*4+p) at shift j=jj-4 needs halo float
            // f = lane*4 + p + 8 - jj  ->  jj=8 -> xv0 ... jj=0 -> xv2
            const f4 w8 = xv0;
            const f4 w7 = __builtin_shufflevector(xv0, xv1, 1, 2, 3, 4);
            const f4 w6 = __builtin_shufflevector(xv0, xv1, 2, 3, 4, 5);
            const f4 w5 = __builtin_shufflevector(xv0, xv1, 3, 4, 5, 6);
            const f4 w4 = xv1;
            const f4 w3 = __builtin_shufflevector(xv1, xv2, 1, 2, 3, 4);
            const f4 w2 = __builtin_shufflevector(xv1, xv2, 2, 3, 4, 5);
            const f4 w1w = __builtin_shufflevector(xv1, xv2, 3, 4, 5, 6);
            const f4 w0w = xv2;
            acc0 = __builtin_elementwise_fma(av, w0w, acc0);
            acc1 = __builtin_elementwise_fma(av, w1w, acc1);
            acc2 = __builtin_elementwise_fma(av, w2, acc2);
            acc3 = __builtin_elementwise_fma(av, w3, acc3);
            acc4 = __builtin_elementwise_fma(av, w4, acc4);
            acc5 = __builtin_elementwise_fma(av, w5, acc5);
            acc6 = __builtin_elementwise_fma(av, w6, acc6);
            acc7 = __builtin_elementwise_fma(av, w7, acc7);
            acc8 = __builtin_elementwise_fma(av, w8, acc8);
        }
        __syncthreads();
    }

    // ---- epilogue ----
    const float scale = 1.0f / 81.0f;
    const int hout = h0 + wave;
    const int wout = lane * 4;
    // k = (9*i + j) mod 81, i = ib-4, j = jj-4 -> (9*ib + jj + 41) mod 81
#define CV_OUT(JJ)                                                           \
    {                                                                        \
        const int k = (9 * ib + (JJ) + 41) % 81;                             \
        float* po = out + (((long)b * 81 + k) * HH + hout) * WW + wout;      \
        *(f4*)po = acc##JJ * scale;                                          \
    }
    CV_OUT(0) CV_OUT(1) CV_OUT(2) CV_OUT(3) CV_OUT(4)
    CV_OUT(5) CV_OUT(6) CV_OUT(7) CV_OUT(8)
#undef CV_OUT
}

extern "C" void kernel_launch(void* const* d_in, const int* in_sizes, int n_in,
                              void* d_out, int out_size, void* d_ws, size_t ws_size,
                              hipStream_t stream) {
    const float* x1 = (const float*)d_in[0];
    const float* x2 = (const float*)d_in[1];
    float* out = (float*)d_out;
    dim3 grid(8 * 24 * 9);   // 1728 blocks: b * h-tiles * 9 shifts (i fastest)
    dim3 block(THREADS);
    hipLaunchKernelGGL(cost_volume_kernel, grid, block, 0, stream, x1, x2, out);
}

// Round 13
// 113.951 us; speedup vs baseline: 2.0323x; 2.0323x over previous
//
#include <hip/hip_runtime.h>

#define HH 192
#define WW 256
#define TH 4              // tile rows
#define TW 64             // tile cols
#define CCH 8             // channels per chunk
#define NCHUNK 8          // 64 / 8
#define THREADS 576       // 9 waves; wave w handles i = w - 4
#define CHSTEP (CCH * HH * WW)

// x2 halo band: 12 rows x 72 floats (18 x 16B units) per channel
#define X2_RU   18
#define X2_ROWS 12
#define X2_CHF  (X2_ROWS * X2_RU * 4)   // 864 floats per channel
#define BUFF2   (CCH * X2_CHF)          // 6912 floats per buffer
#define X1_CHF  (TH * TW)               // 256 floats per channel
#define BUFF1   (CCH * X1_CHF)          // 2048 floats per buffer
#define S1_OFF  (2 * BUFF2)             // 13824

typedef float f4 __attribute__((ext_vector_type(4)));

// async global->LDS, 16B per lane, dest = wave-uniform base + lane*16
#define GLL(gp, lp) __builtin_amdgcn_global_load_lds(                        \
    (const __attribute__((address_space(1))) unsigned int*)(gp),            \
    (__attribute__((address_space(3))) unsigned int*)(lp), 16, 0, 0)

// R13: conflict-free retile. Model fitting R6-R12 counters: ds_read_b128 is
// processed in 16-lane groups (256B); a group reading ONE contiguous run =
// 0 conflicts (R12 measured 0; x1 stride-32 measured 0); a group spanning
// 2 rows pays +4..8 cyc (R8/R6). So: tile 4 rows x 64 px, lane=(r=lane>>4,
// wcg=lane&15) -> every read's 16-lane group covers one row contiguously.
// Keeps R11's i-per-wave / LDS-staging / window-shuffle structure.
__global__ __launch_bounds__(THREADS) void cost_volume_kernel(
    const float* __restrict__ x1, const float* __restrict__ x2,
    float* __restrict__ out)
{
    __shared__ __align__(16) float smem[2 * BUFF2 + 2 * BUFF1];  // 70 KiB

    const int tid  = threadIdx.x;
    const int wave = tid >> 6;      // 0..8 -> i = wave - 4
    const int lane = tid & 63;
    const int r    = lane >> 4;     // 0..3 tile row
    const int wcg  = lane & 15;     // 0..15 col group (4 px each)

    const int bid = blockIdx.x;
    const int b   = bid / 192;      // 48 h-tiles * 4 w-tiles
    const int rem = bid % 192;
    const int h0  = (rem >> 2) * TH;
    const int w0  = (rem & 3) * TW;

    // ---- x2 staging: [8 ch][12 rows][18 units] = 1728 units = 27 strips ----
    // unit u -> ch=u/216, row=(u%216)/18, cu=u%18; global col = w0-4+4cu.
    // LDS float offset = 4u (linear). wave w does strips {w, w+9, w+18}.
    auto desc2 = [&](int s, int& goff) {   // -1 if masked
        const int u = (s << 6) + lane;
        const int ch = u / 216, rm = u % 216;
        const int row = rm / 18, cu = rm % 18;
        const int hg = h0 - 4 + row, wg = w0 - 4 + (cu << 2);
        const bool v = (hg >= 0) & (hg < HH) & (wg >= 0) & (wg <= WW - 4);
        goff = v ? (((b * 64 + ch) * HH + hg) * WW + wg) : -1;
    };
    int gA, gB, gC;
    desc2(wave, gA);
    desc2(wave + 9, gB);
    desc2(wave + 18, gC);

    // ---- x1 staging: strip s = channel s; waves 1..8 do s = wave-1 ----
    const bool v1 = (wave >= 1);
    const int s1 = (wave - 1) & 7;
    const int g1 = ((b * 64 + s1) * HH + (h0 + (lane >> 4))) * WW +
                   w0 + ((lane & 15) << 2);

    auto issue = [&](int nb, int n) {
        const int cofs = n * CHSTEP;
        float* const b2 = smem + nb * BUFF2;
        float* const b1 = smem + S1_OFF + nb * BUFF1;
        if (gA >= 0) GLL(x2 + gA + cofs, b2 + (wave << 8));
        if (gB >= 0) GLL(x2 + gB + cofs, b2 + ((wave + 9) << 8));
        if (gC >= 0) GLL(x2 + gC + cofs, b2 + ((wave + 18) << 8));
        if (v1)      GLL(x1 + g1 + cofs, b1 + (s1 << 8));
    };

    // ---- pre-zero LDS (halo/OOB slots persist as zeros) ----
    const f4 z4 = {0.f, 0.f, 0.f, 0.f};
    for (int z = tid; z < (2 * BUFF2 + 2 * BUFF1) / 4; z += THREADS)
        ((f4*)smem)[z] = z4;
    __syncthreads();

    issue(0, 0);
    __syncthreads();   // drains vmcnt(0) before s_barrier

    f4 acc0 = z4, acc1 = z4, acc2 = z4, acc3 = z4, acc4 = z4,
       acc5 = z4, acc6 = z4, acc7 = z4, acc8 = z4;

    const int row2 = r + 8 - wave;   // x2 band row, in [0,11]

    for (int n = 0; n < NCHUNK; ++n) {
        if (n + 1 < NCHUNK) issue((n + 1) & 1, n + 1);
        const float* sb2 = smem + (n & 1) * BUFF2 + row2 * (X2_RU * 4) + (wcg << 2);
        const float* sb1 = smem + S1_OFF + (n & 1) * BUFF1 + r * TW + (wcg << 2);
#pragma unroll
        for (int cc = 0; cc < CCH; ++cc) {
            const f4 av  = *(const f4*)(sb1 + cc * X1_CHF);
            const f4 xv0 = *(const f4*)(sb2 + cc * X2_CHF);
            const f4 xv1 = *(const f4*)(sb2 + cc * X2_CHF + 4);
            const f4 xv2 = *(const f4*)(sb2 + cc * X2_CHF + 8);
            // px p (w = w0+4wcg+p) at shift j=jj-4 needs band float
            // 4wcg + p + 8 - jj  ->  jj=8 -> xv0 ... jj=0 -> xv2
            const f4 w8 = xv0;
            const f4 w7 = __builtin_shufflevector(xv0, xv1, 1, 2, 3, 4);
            const f4 w6 = __builtin_shufflevector(xv0, xv1, 2, 3, 4, 5);
            const f4 w5 = __builtin_shufflevector(xv0, xv1, 3, 4, 5, 6);
            const f4 w4 = xv1;
            const f4 w3 = __builtin_shufflevector(xv1, xv2, 1, 2, 3, 4);
            const f4 w2 = __builtin_shufflevector(xv1, xv2, 2, 3, 4, 5);
            const f4 w1w = __builtin_shufflevector(xv1, xv2, 3, 4, 5, 6);
            const f4 w0w = xv2;
            acc0 = __builtin_elementwise_fma(av, w0w, acc0);
            acc1 = __builtin_elementwise_fma(av, w1w, acc1);
            acc2 = __builtin_elementwise_fma(av, w2, acc2);
            acc3 = __builtin_elementwise_fma(av, w3, acc3);
            acc4 = __builtin_elementwise_fma(av, w4, acc4);
            acc5 = __builtin_elementwise_fma(av, w5, acc5);
            acc6 = __builtin_elementwise_fma(av, w6, acc6);
            acc7 = __builtin_elementwise_fma(av, w7, acc7);
            acc8 = __builtin_elementwise_fma(av, w8, acc8);
        }
        __syncthreads();
    }

    // ---- epilogue ----
    const float scale = 1.0f / 81.0f;
    const int hout = h0 + r;
    const int wout = w0 + (wcg << 2);
    // k = (9*i + j) mod 81 = (9*wave + jj + 41) mod 81
#define CV_OUT(JJ)                                                           \
    {                                                                        \
        const int k = (9 * wave + (JJ) + 41) % 81;                           \
        float* po = out + (((long)b * 81 + k) * HH + hout) * WW + wout;      \
        *(f4*)po = acc##JJ * scale;                                          \
    }
    CV_OUT(0) CV_OUT(1) CV_OUT(2) CV_OUT(3) CV_OUT(4)
    CV_OUT(5) CV_OUT(6) CV_OUT(7) CV_OUT(8)
#undef CV_OUT
}

extern "C" void kernel_launch(void* const* d_in, const int* in_sizes, int n_in,
                              void* d_out, int out_size, void* d_ws, size_t ws_size,
                              hipStream_t stream) {
    const float* x1 = (const float*)d_in[0];
    const float* x2 = (const float*)d_in[1];
    float* out = (float*)d_out;
    dim3 grid(8 * 48 * 4);   // 1536 blocks: 8 b * 48 h-tiles * 4 w-tiles
    dim3 block(THREADS);
    hipLaunchKernelGGL(cost_volume_kernel, grid, block, 0, stream, x1, x2, out);
}